// Round 7
// baseline (672.935 us; speedup 1.0000x reference)
//
#include <hip/hip_runtime.h>
#include <hip/hip_bf16.h>
#include <math.h>

// N=4, H=W=64, C=256, G=8, GC=32, K=3, P=9, pad=1. Padded spatial: 66x66.
// Persistent mega-kernel: 512 blocks (2/CU), 10 phases, 9 device-scope grid syncs.

#define NBLK 512

typedef __attribute__((ext_vector_type(8))) short bf16x8;
typedef __attribute__((ext_vector_type(4))) float f32x4;

__device__ __forceinline__ float blo(unsigned u){
  union { unsigned int i; float f; } v; v.i = u<<16; return v.f;
}
__device__ __forceinline__ float bhi(unsigned u){
  union { unsigned int i; float f; } v; v.i = u & 0xffff0000u; return v.f;
}
__device__ __forceinline__ unsigned short f2b(float f){
  __hip_bfloat16 h = __float2bfloat16(f);
  return *reinterpret_cast<unsigned short*>(&h);
}
__device__ __forceinline__ unsigned pk2(float lo, float hi){
  return (unsigned)f2b(lo) | ((unsigned)f2b(hi)<<16);
}

__device__ __forceinline__ void gload16(const void* g, void* l){
  auto gp = reinterpret_cast<const __attribute__((address_space(1))) unsigned*>(
      reinterpret_cast<uintptr_t>(g));
  auto lp = reinterpret_cast<__attribute__((address_space(3))) unsigned*>(
      reinterpret_cast<uintptr_t>(l));
  __builtin_amdgcn_global_load_lds(gp, lp, 16, 0, 0);
}

// ---- device-scope grid barrier (all NBLK blocks co-resident) ----
__device__ __forceinline__ void gridsync(unsigned* c){
  __syncthreads();
  if (threadIdx.x == 0){
    __threadfence();                                    // release: flush writes device-wide
    atomicAdd(c, 1u);
    while (__hip_atomic_load(c, __ATOMIC_RELAXED, __HIP_MEMORY_SCOPE_AGENT) < (unsigned)NBLK)
      __builtin_amdgcn_s_sleep(1);
    __threadfence();                                    // acquire: invalidate stale cache
  }
  __syncthreads();
}

// ---------------- prep unit: weight transposes + offmask + stats zero + R3 border + NCHW->NHWC ----------------
__device__ void prep_unit(int b, char* smem,
    const float* __restrict__ x,
    const float* __restrict__ w_in, const float* __restrict__ w_out,
    const float* __restrict__ conv1_w, const float* __restrict__ down_w,
    const float* __restrict__ w_off, const float* __restrict__ w_mask,
    const float* __restrict__ b_off, const float* __restrict__ b_mask,
    __hip_bfloat16* __restrict__ w_inT, __hip_bfloat16* __restrict__ w_outT,
    __hip_bfloat16* __restrict__ c1T, __hip_bfloat16* __restrict__ dnT,
    __hip_bfloat16* __restrict__ w_omT, float* __restrict__ bias_om,
    float* __restrict__ stats, __hip_bfloat16* __restrict__ R3,
    __hip_bfloat16* __restrict__ xs)
{
  __syncthreads();           // protect previous unit's LDS reads
  if (b < 160){
    float (*tl)[257] = (float(*)[257])smem;
    const float* W; __hip_bfloat16* WT; int Kd, kb;
    if (b < 8)      { W = w_in;    WT = w_inT;  Kd = 256;  kb = b; }
    else if (b <16) { W = w_out;   WT = w_outT; Kd = 256;  kb = b-8; }
    else if (b <88) { W = conv1_w; WT = c1T;    Kd = 2304; kb = b-16; }
    else            { W = down_w;  WT = dnT;    Kd = 2304; kb = b-88; }
    int k0 = kb*32;
    #pragma unroll
    for (int dk=0; dk<32; dk++) tl[dk][threadIdx.x] = W[(size_t)(k0+dk)*256 + threadIdx.x];
    __syncthreads();
    #pragma unroll
    for (int r=0; r<32; r++){
      int co = r*8 + (threadIdx.x>>5);
      int dk = threadIdx.x&31;
      WT[(size_t)co*Kd + k0 + dk] = __float2bfloat16(tl[dk][co]);
    }
  } else if (b < 416){
    int n = b - 160, k = threadIdx.x;
    float v = (n<144) ? w_off[(size_t)k*144 + n] : (n<216 ? w_mask[(size_t)k*72 + (n-144)] : 0.f);
    w_omT[(size_t)n*256 + k] = __float2bfloat16(v);
    if (k==0) bias_om[n] = (n<144) ? b_off[n] : (n<216 ? b_mask[n-144] : 0.f);
  } else if (b < 546){
    int gid = (b-416)*8 + (threadIdx.x>>5);
    if (gid >= 1040) return;
    int n = gid/260; int ci = gid - n*260;
    int r, c;
    if (ci < 66){ r = 0; c = ci; }
    else if (ci < 132){ r = 65; c = ci-66; }
    else { int q = ci-132; r = 1 + (q>>1); c = (q&1) ? 65 : 0; }
    uint4* p = (uint4*)(R3 + ((size_t)((n*66+r)*66+c))*256) + (threadIdx.x&31);
    *p = make_uint4(0,0,0,0);
  } else if (b == 546){
    stats[threadIdx.x] = 0.f;
    stats[256+threadIdx.x] = 0.f;
    stats[512+threadIdx.x] = 0.f;
  } else {
    // NCHW fp32 -> NHWC bf16 transpose, 32x32 tile
    float (*tile)[33] = (float(*)[33])smem;
    int t = b - 547;                 // 0..4095
    int n = t >> 10;
    int c0 = ((t >> 7) & 7) * 32;
    int hw0 = (t & 127) * 32;
    int tx = threadIdx.x & 31, ty = threadIdx.x >> 5;
    #pragma unroll
    for (int ii=0; ii<4; ii++){
      int ci = ty + ii*8;
      tile[ci][tx] = x[(size_t)(n*256 + c0+ci)*4096 + hw0 + tx];
    }
    __syncthreads();
    #pragma unroll
    for (int ii=0; ii<4; ii++){
      int hwi = ty + ii*8;
      xs[((size_t)n*4096 + hw0+hwi)*256 + c0 + tx] = __float2bfloat16(tile[tx][hwi]);
    }
  }
}

#define WAITV(n) asm volatile("s_waitcnt vmcnt(" #n ")" ::: "memory")

// ---------------- MFMA GEMM / implicit conv body, 3-buf counted-vmcnt pipeline ----------------
// AMODE 0: A=[M][KTOT] bf16. AMODE 1: A=(4,66,66,256) padded bf16, implicit 3x3, stride STRIDE.
// OMODE 0: bf16 [M][256]+bias. OMODE 1: bf16 padded +bias. OMODE 2: fp32 ldc=216 col<216.
template<int AMODE, int OMODE, int STRIDE, int KTOT, int NSHIFT, int AROWS, int NWG>
__device__ void mm_body(int id,
    const __hip_bfloat16* __restrict__ A, const __hip_bfloat16* __restrict__ Bt,
    const float* __restrict__ bias, float* __restrict__ OF, __hip_bfloat16* __restrict__ OH,
    float* __restrict__ stats, char* ldsc)
{
  constexpr int MI = AROWS/32;
  constexpr int WROWS = AROWS/2;
  constexpr int JA = AROWS/32;
  constexpr int SL = JA + 4;                 // loads per stage
  constexpr int BUFSZ = AROWS*128 + 16384;
  const int tid = threadIdx.x;
  const int lane = tid & 63;
  const int wv = tid >> 6;
  const int wr = wv >> 1, wc = wv & 1;

  // XCD-chunked bijective swizzle (NWG % 8 == 0)
  int sw = (id & 7) * (NWG >> 3) + (id >> 3);
  const int m0 = (sw >> 1) * AROWS, n0 = (sw & 1) * 128;

  const int swz_s = ((tid >> 3) & 7) << 4;
  const int cby = ((tid & 7) << 4) ^ swz_s;
  const int kl = cby >> 1;
  int aoff[JA], boff[4];
  #pragma unroll
  for (int j=0;j<JA;j++){
    int row = j*32 + (tid>>3);
    if (AMODE==0){
      aoff[j] = (m0 + row) * KTOT + kl;
    } else {
      int m = m0 + row;
      int n, ho, wo;
      if (STRIDE==1){ n = m>>12; ho = (m>>6)&63; wo = m&63; }
      else          { n = m>>10; ho = (m>>5)&31; wo = m&31; }
      aoff[j] = ((n*66 + ho*STRIDE)*66 + wo*STRIDE)*256 + kl;
    }
  }
  #pragma unroll
  for (int j=0;j<4;j++) boff[j] = (n0 + j*32 + (tid>>3)) * KTOT + kl;
  char* ldsst = ldsc + wv*1024;

  const int fr = lane & 15;
  const int kb = (lane >> 4) << 4;
  const int swz_r = (fr & 7) << 4;
  int aRow[MI], bRow[4];
  #pragma unroll
  for (int i=0;i<MI;i++) aRow[i] = (wr*WROWS + i*16 + fr) * 128;
  #pragma unroll
  for (int i=0;i<4;i++)  bRow[i] = AROWS*128 + (wc*64 + i*16 + fr) * 128;
  int cb[2];
  cb[0] = kb ^ swz_r;
  cb[1] = (64 | kb) ^ swz_r;

  // bias loads FIRST so the vmcnt FIFO counts only stage loads after them
  float bn[4];
  #pragma unroll
  for (int ni=0;ni<4;ni++) bn[ni] = bias[n0 + wc*64 + ni*16 + fr];

  f32x4 acc[MI][4];
  #pragma unroll
  for (int mi=0;mi<MI;mi++)
    #pragma unroll
    for (int ni=0;ni<4;ni++)
      acc[mi][ni] = (f32x4){0.f,0.f,0.f,0.f};

  auto STAGE = [&](int buf, int t){
    const int k0 = t*64;
    int astep;
    if (AMODE==1){
      int tap = k0 >> 8;
      int kh = (tap>=6) ? 2 : (tap>=3 ? 1 : 0);
      int kw = tap - kh*3;
      astep = (kh*66 + kw)*256 + (k0 & 255);
    } else astep = k0;
    char* db = ldsst + buf*BUFSZ;
    #pragma unroll
    for (int j=0;j<JA;j++) gload16(A + aoff[j] + astep, db + j*4096);
    #pragma unroll
    for (int j=0;j<4;j++)  gload16(Bt + boff[j] + k0, db + AROWS*128 + j*4096);
  };

  constexpr int NT = KTOT / 64;
  STAGE(0, 0);
  STAGE(1, 1);
  if constexpr (SL==6) WAITV(6); else WAITV(5);
  __builtin_amdgcn_s_barrier();
  __builtin_amdgcn_sched_barrier(0);
  for (int t=0; t<NT; ++t){
    if (t+2 < NT) STAGE((t+2)%3, t+2);
    char* cbase = ldsc + (t%3)*BUFSZ;
    __builtin_amdgcn_s_setprio(1);
    #pragma unroll
    for (int kk=0; kk<2; kk++){
      bf16x8 av[MI], bv[4];
      #pragma unroll
      for (int i=0;i<MI;i++) av[i] = *(const bf16x8*)(cbase + aRow[i] + cb[kk]);
      #pragma unroll
      for (int i=0;i<4;i++)  bv[i] = *(const bf16x8*)(cbase + bRow[i] + cb[kk]);
      #pragma unroll
      for (int mi=0;mi<MI;mi++)
        #pragma unroll
        for (int ni=0;ni<4;ni++)
          acc[mi][ni] = __builtin_amdgcn_mfma_f32_16x16x32_bf16(av[mi], bv[ni], acc[mi][ni], 0,0,0);
    }
    __builtin_amdgcn_s_setprio(0);
    if (t < NT-1){
      if (t+2 < NT){ if constexpr (SL==6) WAITV(6); else WAITV(5); }
      else WAITV(0);
      __builtin_amdgcn_s_barrier();
      __builtin_amdgcn_sched_barrier(0);
    }
  }

  float sni[4] = {0.f,0.f,0.f,0.f};
  float qni[4] = {0.f,0.f,0.f,0.f};
  #pragma unroll
  for (int mi=0;mi<MI;mi++){
    #pragma unroll
    for (int r=0;r<4;r++){
      int gr = m0 + wr*WROWS + mi*16 + (lane>>4)*4 + r;
      #pragma unroll
      for (int ni=0;ni<4;ni++){
        int gc = n0 + wc*64 + ni*16 + fr;
        float v = acc[mi][ni][r] + bn[ni];
        if (NSHIFT){ sni[ni] += v; qni[ni] += v*v; }
        if (OMODE==0){
          OH[(size_t)gr*256 + gc] = __float2bfloat16(v);
        } else if (OMODE==1){
          int n = gr>>12, h = (gr>>6)&63, w = gr&63;
          OH[((size_t)((n*66)+(h+1))*66 + (w+1))*256 + gc] = __float2bfloat16(v);
        } else {
          if (gc < 216) OF[(size_t)gr*216 + gc] = v;
        }
      }
    }
  }
  if (NSHIFT){
    #pragma unroll
    for (int ni=0;ni<4;ni++){
      #pragma unroll
      for (int msk=16; msk<64; msk<<=1){
        sni[ni] += __shfl_xor(sni[ni], msk);
        qni[ni] += __shfl_xor(qni[ni], msk);
      }
      #pragma unroll
      for (int msk=1; msk<8; msk<<=1){
        sni[ni] += __shfl_xor(sni[ni], msk);
        qni[ni] += __shfl_xor(qni[ni], msk);
      }
    }
    __syncthreads();                 // all waves out of K-loop before LDS reuse
    float* ls = (float*)ldsc;
    if (tid < 32) ls[tid] = 0.f;
    __syncthreads();
    if ((lane & 7) == 0 && (lane & 48) == 0){
      int oct = (lane>>3) & 1;
      #pragma unroll
      for (int ni=0;ni<4;ni++){
        int idx = wc*8 + ni*2 + oct;
        atomicAdd(&ls[idx], sni[ni]);
        atomicAdd(&ls[16+idx], qni[ni]);
      }
    }
    __syncthreads();
    if (tid < 16){
      int gg = (m0>>NSHIFT)*32 + (n0>>3) + tid;
      atomicAdd(&stats[gg*2+0], ls[tid]);
      atomicAdd(&stats[gg*2+1], ls[16+tid]);
    }
  }
}

// ---------------- depthwise conv 3x3 + LayerNorm + GELU unit (weights pre-staged in LDS) ----------------
__device__ void dwln_unit(int l, const __hip_bfloat16* __restrict__ xs,
    const float* lw, const float* lb, const float* lg, const float* lbt,
    __hip_bfloat16* __restrict__ t)
{
  int tid = threadIdx.x;
  int posl = tid>>5, cg = tid&31, c0 = cg*8;
  int pos = l*8 + posl;
  int nb = pos>>12, h = (pos>>6)&63, w = pos&63;
  float v[8];
  #pragma unroll
  for (int k=0;k<8;k++) v[k] = lb[c0+k];
  #pragma unroll
  for (int kh=0;kh<3;kh++){
    int hin = h+kh-1;
    if (hin<0||hin>=64) continue;
    #pragma unroll
    for (int kw=0;kw<3;kw++){
      int win = w+kw-1;
      if (win<0||win>=64) continue;
      const unsigned short* xr = (const unsigned short*)xs + ((size_t)((nb*64+hin)*64+win))*256 + c0;
      uint4 u = *(const uint4*)xr;
      const float* wr = &lw[(kh*3+kw)*256 + c0];
      v[0] += blo(u.x)*wr[0]; v[1] += bhi(u.x)*wr[1];
      v[2] += blo(u.y)*wr[2]; v[3] += bhi(u.y)*wr[3];
      v[4] += blo(u.z)*wr[4]; v[5] += bhi(u.z)*wr[5];
      v[6] += blo(u.w)*wr[6]; v[7] += bhi(u.w)*wr[7];
    }
  }
  float s=0.f, s2=0.f;
  #pragma unroll
  for (int k=0;k<8;k++){ s += v[k]; s2 += v[k]*v[k]; }
  #pragma unroll
  for (int m=1;m<32;m<<=1){ s += __shfl_xor(s,m); s2 += __shfl_xor(s2,m); }
  float mu = s*(1.f/256.f);
  float var = s2*(1.f/256.f) - mu*mu;
  float rstd = rsqrtf(var + 1e-5f);
  float ge[8];
  #pragma unroll
  for (int k=0;k<8;k++){
    float xn = (v[k]-mu)*rstd*lg[c0+k] + lbt[c0+k];
    ge[k] = 0.5f*xn*(1.f + erff(xn*0.70710678118654752f));
  }
  uint4 o;
  o.x = pk2(ge[0],ge[1]); o.y = pk2(ge[2],ge[3]);
  o.z = pk2(ge[4],ge[5]); o.w = pk2(ge[6],ge[7]);
  *(uint4*)((unsigned short*)t + (size_t)pos*256 + c0) = o;
}

// ---------------- DCNv3 sampling unit: D staged in LDS, 8ch/lane, fused softmax ----------------
__device__ void sample_unit(int l, const float* Ds,
    const __hip_bfloat16* __restrict__ xp, __hip_bfloat16* __restrict__ y)
{
  int tid = threadIdx.x;
  int pp = tid>>5;
  int g = (tid>>2)&7, li = tid&3;
  int pos = l*8 + pp;
  int nb = pos >> 12, h = (pos >> 6) & 63, w = pos & 63;
  const float* offp = Ds + pp*216 + g*18;
  const float* mskp = Ds + pp*216 + 144 + g*9;
  float mr[9];
  #pragma unroll
  for (int p=0;p<9;p++) mr[p] = mskp[p];
  float mx = mr[0];
  #pragma unroll
  for (int p=1;p<9;p++) mx = fmaxf(mx, mr[p]);
  float ssum = 0.f;
  #pragma unroll
  for (int p=0;p<9;p++){ mr[p] = __expf(mr[p]-mx); ssum += mr[p]; }
  float rinv = 1.f/ssum;
  const unsigned short* img = (const unsigned short*)xp + (size_t)nb*4356*256 + g*32 + li*8;
  float a0=0,a1=0,a2=0,a3=0,a4=0,a5=0,a6=0,a7=0;
  #pragma unroll
  for (int p=0;p<9;p++){
    int di = p/3 - 1, dj = p%3 - 1;
    float ox = offp[p*2], oy = offp[p*2+1];
    float px = (float)(w + 1 + di) + ox;
    float py = (float)(h + 1 + dj) + oy;
    float x0f = floorf(px), y0f = floorf(py);
    float wx1 = px - x0f, wy1 = py - y0f;
    float wx0 = 1.f - wx1, wy0 = 1.f - wy1;
    int x0 = (int)x0f, y0 = (int)y0f;
    float s0=0,s1=0,s2=0,s3=0,s4=0,s5=0,s6=0,s7=0;
    #pragma unroll
    for (int cy=0;cy<2;cy++){
      int yi = y0+cy;
      if (yi<0||yi>=66) continue;
      float wy = cy ? wy1 : wy0;
      #pragma unroll
      for (int cx=0;cx<2;cx++){
        int xi = x0+cx;
        if (xi<0||xi>=66) continue;
        float wq = (cx ? wx1 : wx0)*wy;
        uint4 u = *(const uint4*)(img + (size_t)(yi*66+xi)*256);
        s0 += blo(u.x)*wq; s1 += bhi(u.x)*wq;
        s2 += blo(u.y)*wq; s3 += bhi(u.y)*wq;
        s4 += blo(u.z)*wq; s5 += bhi(u.z)*wq;
        s6 += blo(u.w)*wq; s7 += bhi(u.w)*wq;
      }
    }
    float mp = mr[p]*rinv;
    a0 += s0*mp; a1 += s1*mp; a2 += s2*mp; a3 += s3*mp;
    a4 += s4*mp; a5 += s5*mp; a6 += s6*mp; a7 += s7*mp;
  }
  uint4 o;
  o.x = pk2(a0,a1); o.y = pk2(a2,a3); o.z = pk2(a4,a5); o.w = pk2(a6,a7);
  *(uint4*)((unsigned short*)y + (size_t)pos*256 + g*32 + li*8) = o;
}

// ---------------- GN apply + SiLU -> padded bf16, main unit ----------------
__device__ void gnap_main(int u, const __hip_bfloat16* __restrict__ X,
    const float* __restrict__ stats, const float* __restrict__ gamma,
    const float* __restrict__ beta, __hip_bfloat16* __restrict__ OH)
{
  int tid = threadIdx.x;
  int row = u*8 + (tid>>5);
  int grp = tid & 31;
  int c0 = grp*8;
  int nb = row >> 12;
  float S  = stats[(nb*32+grp)*2+0];
  float S2 = stats[(nb*32+grp)*2+1];
  const float inv = 1.f/32768.f;
  float mu = S*inv;
  float rs = rsqrtf(S2*inv - mu*mu + 1e-5f);
  float4 g0 = *(const float4*)(gamma + c0), g1 = *(const float4*)(gamma + c0 + 4);
  float4 bt0 = *(const float4*)(beta + c0), bt1 = *(const float4*)(beta + c0 + 4);
  uint4 u4 = *(const uint4*)((const unsigned short*)X + (size_t)row*256 + c0);
  float v[8] = { blo(u4.x), bhi(u4.x), blo(u4.y), bhi(u4.y), blo(u4.z), bhi(u4.z), blo(u4.w), bhi(u4.w) };
  float gm[8] = { g0.x,g0.y,g0.z,g0.w,g1.x,g1.y,g1.z,g1.w };
  float bb[8] = { bt0.x,bt0.y,bt0.z,bt0.w,bt1.x,bt1.y,bt1.z,bt1.w };
  #pragma unroll
  for (int k=0;k<8;k++){
    float t = (v[k]-mu)*rs*gm[k] + bb[k];
    v[k] = t / (1.f + expf(-t));
  }
  int h = (row>>6)&63, w = row&63;
  uint4 o;
  o.x = pk2(v[0],v[1]); o.y = pk2(v[2],v[3]); o.z = pk2(v[4],v[5]); o.w = pk2(v[6],v[7]);
  *(uint4*)((unsigned short*)OH + ((size_t)((nb*66)+(h+1))*66 + (w+1))*256 + c0) = o;
}

__device__ void gnap_border(int u, __hip_bfloat16* __restrict__ OH){
  int gid = u*8 + (threadIdx.x>>5);
  if (gid >= 1040) return;
  int n = gid/260; int ci = gid - n*260;
  int r, c;
  if (ci < 66){ r = 0; c = ci; }
  else if (ci < 132){ r = 65; c = ci-66; }
  else { int q = ci-132; r = 1 + (q>>1); c = (q&1) ? 65 : 0; }
  uint4* p = (uint4*)(OH + ((size_t)((n*66+r)*66+c))*256) + (threadIdx.x&31);
  *p = make_uint4(0,0,0,0);
}

// ---------------- GN3 apply -> fp32 NCHW out via LDS transpose ----------------
__device__ void gnout_unit(int u, const __hip_bfloat16* __restrict__ X,
    const float* __restrict__ stats, const float* __restrict__ gamma,
    const float* __restrict__ beta, float* __restrict__ out, char* smem)
{
  float (*val)[1024] = (float(*)[1024])smem;
  int nb = u >> 5, cg = u & 31;
  int c0 = cg*8;
  float S  = stats[(nb*32+cg)*2+0];
  float S2 = stats[(nb*32+cg)*2+1];
  const float inv = 1.f/8192.f;
  float mu = S*inv;
  float rs = rsqrtf(S2*inv - mu*mu + 1e-5f);
  float4 g0 = *(const float4*)(gamma + c0), g1 = *(const float4*)(gamma + c0 + 4);
  float4 bt0 = *(const float4*)(beta + c0), bt1 = *(const float4*)(beta + c0 + 4);
  float gm[8] = { g0.x,g0.y,g0.z,g0.w,g1.x,g1.y,g1.z,g1.w };
  float bb[8] = { bt0.x,bt0.y,bt0.z,bt0.w,bt1.x,bt1.y,bt1.z,bt1.w };
  #pragma unroll
  for (int k=0;k<4;k++){
    int pos = k*256 + threadIdx.x;
    uint4 u4 = *(const uint4*)((const unsigned short*)X + ((size_t)(nb*1024+pos))*256 + c0);
    float v[8] = { blo(u4.x), bhi(u4.x), blo(u4.y), bhi(u4.y), blo(u4.z), bhi(u4.z), blo(u4.w), bhi(u4.w) };
    #pragma unroll
    for (int q=0;q<8;q++) val[q][pos] = (v[q]-mu)*rs*gm[q] + bb[q];
  }
  __syncthreads();
  int ch = threadIdx.x>>5, pl = threadIdx.x&31;
  float* orow = out + (((size_t)(nb*256 + c0 + ch))<<10);
  #pragma unroll
  for (int j=0;j<32;j++) orow[pl + j*32] = val[ch][pl + j*32];
}

// ==================== the mega-kernel ====================
__global__ __launch_bounds__(256, 2) void k_mega(
    const float* __restrict__ x,
    const float* __restrict__ w_in, const float* __restrict__ b_in,
    const float* __restrict__ dw_w, const float* __restrict__ dw_b,
    const float* __restrict__ ln_g, const float* __restrict__ ln_b,
    const float* __restrict__ w_off, const float* __restrict__ b_off,
    const float* __restrict__ w_mask, const float* __restrict__ b_mask,
    const float* __restrict__ w_out, const float* __restrict__ b_out,
    const float* __restrict__ gn1_g, const float* __restrict__ gn1_b,
    const float* __restrict__ conv1_w, const float* __restrict__ conv1_b,
    const float* __restrict__ gn2_g, const float* __restrict__ gn2_b,
    const float* __restrict__ down_w, const float* __restrict__ down_b,
    const float* __restrict__ gn3_g, const float* __restrict__ gn3_b,
    float* __restrict__ out,
    __hip_bfloat16* R0h, float* R1f, __hip_bfloat16* R2,
    __hip_bfloat16* R3, __hip_bfloat16* R4,
    __hip_bfloat16* w_inT, __hip_bfloat16* w_outT, __hip_bfloat16* w_omT,
    __hip_bfloat16* c1T, __hip_bfloat16* dnT,
    float* bias_om, float* stats, unsigned* sync)
{
  __shared__ __align__(16) char SMEM[73728];   // 72 KB -> 2 blocks/CU
  __hip_bfloat16* R1h = (__hip_bfloat16*)R1f;
  const int bid = blockIdx.x;
  const int s8 = bid>>3, x8 = bid&7;           // batch-XCD-local unit mapping

  // ---- P0: prep ----
  for (int b = bid; b < 4643; b += NBLK)
    prep_unit(b, SMEM, x, w_in, w_out, conv1_w, down_w, w_off, w_mask, b_off, b_mask,
              w_inT, w_outT, c1T, dnT, w_omT, bias_om, stats, R3, R2);
  gridsync(sync+0);

  // ---- P1: input_proj (-> padded R3) then depthwise+LN+GELU (-> R4) ----
  mm_body<0,1,1,256,0,64,NBLK>(bid, R2, w_inT, b_in, nullptr, R3, nullptr, SMEM);
  __syncthreads();
  {
    float* lw = (float*)SMEM;
    float* lb = (float*)(SMEM+9216);
    float* lg = (float*)(SMEM+10240);
    float* lbt= (float*)(SMEM+11264);
    int tid = threadIdx.x;
    #pragma unroll
    for (int p=0;p<9;p++) lw[p*256+tid] = dw_w[p*256+tid];
    lb[tid] = dw_b[tid]; lg[tid] = ln_g[tid]; lbt[tid] = ln_b[tid];
    __syncthreads();
    #pragma unroll
    for (int j=0;j<4;j++){
      int l = (x8>>1)*512 + (s8*2+(x8&1))*4 + j;
      dwln_unit(l, R2, lw, lb, lg, lbt, R4);
    }
  }
  gridsync(sync+1);

  // ---- P2: offset+mask GEMM (-> R1f fp32) ----
  mm_body<0,2,1,256,0,64,NBLK>(bid, R4, w_omT, bias_om, R1f, nullptr, nullptr, SMEM);
  gridsync(sync+2);

  // ---- P3: sampling (-> R2) ----
  #pragma unroll
  for (int j=0;j<4;j++){
    int l = (x8>>1)*512 + (s8*2+(x8&1))*4 + j;
    __syncthreads();
    float4* dst = (float4*)SMEM;
    const float4* src = (const float4*)(R1f + (size_t)l*8*216);
    int tid = threadIdx.x;
    if (tid < 216){ dst[tid] = src[tid]; dst[tid+216] = src[tid+216]; }
    __syncthreads();
    sample_unit(l, (const float*)SMEM, R3, R2);
  }
  gridsync(sync+3);

  // ---- P4: output_proj (-> R0h bf16) + GN1 stats ----
  mm_body<0,0,1,256,12,64,NBLK>(bid, R2, w_outT, b_out, nullptr, R0h, stats, SMEM);
  gridsync(sync+4);

  // ---- P5: GN1 + SiLU -> padded R4 (+border) ----
  #pragma unroll
  for (int j=0;j<4;j++){
    int u = (x8>>1)*512 + (s8*2+(x8&1))*4 + j;
    gnap_main(u, R0h, stats, gn1_g, gn1_b, R4);
  }
  for (int u = bid; u < 130; u += NBLK) gnap_border(u, R4);
  gridsync(sync+5);

  // ---- P6: conv1 (-> R1h bf16) + GN2 stats ----
  mm_body<1,0,1,2304,12,64,NBLK>(bid, R4, c1T, conv1_b, nullptr, R1h, stats+256, SMEM);
  gridsync(sync+6);

  // ---- P7: GN2 + SiLU -> padded R3 (+border) ----
  #pragma unroll
  for (int j=0;j<4;j++){
    int u = (x8>>1)*512 + (s8*2+(x8&1))*4 + j;
    gnap_main(u, R1h, stats+256, gn2_g, gn2_b, R3);
  }
  for (int u = bid; u < 130; u += NBLK) gnap_border(u, R3);
  gridsync(sync+7);

  // ---- P8: down conv stride 2 (-> R0h) + GN3 stats (256 blocks) ----
  if (bid < 256)
    mm_body<1,0,2,2304,10,32,256>(bid, R3, dnT, down_b, nullptr, R0h, stats+512, SMEM);
  gridsync(sync+8);

  // ---- P9: GN3 -> out NCHW fp32 (128 blocks) ----
  if (bid < 128)
    gnout_unit(bid, R0h, stats+512, gn3_g, gn3_b, out, SMEM);
}

extern "C" void kernel_launch(void* const* d_in, const int* in_sizes, int n_in,
                              void* d_out, int out_size, void* d_ws, size_t ws_size,
                              hipStream_t stream) {
  const float* x      = (const float*)d_in[0];
  const float* w_in   = (const float*)d_in[1];
  const float* b_in   = (const float*)d_in[2];
  const float* dw_w   = (const float*)d_in[3];
  const float* dw_b   = (const float*)d_in[4];
  const float* ln_g   = (const float*)d_in[5];
  const float* ln_b   = (const float*)d_in[6];
  const float* w_off  = (const float*)d_in[7];
  const float* b_off  = (const float*)d_in[8];
  const float* w_mask = (const float*)d_in[9];
  const float* b_mask = (const float*)d_in[10];
  const float* w_out  = (const float*)d_in[11];
  const float* b_out  = (const float*)d_in[12];
  const float* gn1_g  = (const float*)d_in[13];
  const float* gn1_b  = (const float*)d_in[14];
  const float* conv1_w= (const float*)d_in[15];
  const float* conv1_b= (const float*)d_in[16];
  const float* gn2_g  = (const float*)d_in[17];
  const float* gn2_b  = (const float*)d_in[18];
  const float* down_w = (const float*)d_in[19];
  const float* down_b = (const float*)d_in[20];
  const float* gn3_g  = (const float*)d_in[21];
  const float* gn3_b  = (const float*)d_in[22];
  float* out = (float*)d_out;

  char* wsb = (char*)d_ws;
  __hip_bfloat16* R0h = (__hip_bfloat16*)wsb;             // 8 MB bf16 (y2 / down-out)
  float* R1f = (float*)(wsb + 16777216);                  // fp32 offmask / bf16 conv1-out
  __hip_bfloat16* R2 = (__hip_bfloat16*)(wsb + 33554432); // 8 MB bf16 (xs -> agg)
  __hip_bfloat16* R3 = (__hip_bfloat16*)(wsb + 41943040); // 8.92 MB bf16 (xp -> gn2pad)
  __hip_bfloat16* R4 = (__hip_bfloat16*)(wsb + 50864128); // 8.92 MB bf16 (t -> gn1pad)
  char* R5 = wsb + 59785216;
  __hip_bfloat16* w_inT  = (__hip_bfloat16*)R5;
  __hip_bfloat16* w_outT = (__hip_bfloat16*)(R5 + 131072);
  __hip_bfloat16* w_omT  = (__hip_bfloat16*)(R5 + 262144);
  __hip_bfloat16* c1T    = (__hip_bfloat16*)(R5 + 393216);
  __hip_bfloat16* dnT    = (__hip_bfloat16*)(R5 + 1572864);
  float* bias_om         = (float*)(R5 + 2752512);
  float* stats           = (float*)(R5 + 2753536);        // 768 floats
  unsigned* syncc        = (unsigned*)(R5 + 2756608);     // 16 uints

  hipMemsetAsync(syncc, 0, 64, stream);
  k_mega<<<NBLK, 256, 0, stream>>>(
      x, w_in, b_in, dw_w, dw_b, ln_g, ln_b, w_off, b_off, w_mask, b_mask,
      w_out, b_out, gn1_g, gn1_b, conv1_w, conv1_b, gn2_g, gn2_b,
      down_w, down_b, gn3_g, gn3_b, out,
      R0h, R1f, R2, R3, R4, w_inT, w_outT, w_omT, c1T, dnT,
      bias_om, stats, syncc);
}

// Round 8
// 244.511 us; speedup vs baseline: 2.7522x; 2.7522x over previous
//
#include <hip/hip_runtime.h>
#include <hip/hip_bf16.h>
#include <math.h>

// N=4, H=W=64, C=256, G=8, GC=32, K=3, P=9, pad=1. Padded spatial: 66x66.

typedef __attribute__((ext_vector_type(8))) short bf16x8;
typedef __attribute__((ext_vector_type(4))) float f32x4;

__device__ __forceinline__ float blo(unsigned u){
  union { unsigned int i; float f; } v; v.i = u<<16; return v.f;
}
__device__ __forceinline__ float bhi(unsigned u){
  union { unsigned int i; float f; } v; v.i = u & 0xffff0000u; return v.f;
}
__device__ __forceinline__ unsigned short f2b(float f){
  __hip_bfloat16 h = __float2bfloat16(f);
  return *reinterpret_cast<unsigned short*>(&h);
}
__device__ __forceinline__ unsigned pk2(float lo, float hi){
  return (unsigned)f2b(lo) | ((unsigned)f2b(hi)<<16);
}

__device__ __forceinline__ void gload16(const void* g, void* l){
  auto gp = reinterpret_cast<const __attribute__((address_space(1))) unsigned*>(
      reinterpret_cast<uintptr_t>(g));
  auto lp = reinterpret_cast<__attribute__((address_space(3))) unsigned*>(
      reinterpret_cast<uintptr_t>(l));
  __builtin_amdgcn_global_load_lds(gp, lp, 16, 0, 0);
}

#define WAITV(n) asm volatile("s_waitcnt vmcnt(" #n ")" ::: "memory")

// ---------------- fused prep: weight transposes + offmask + stats zero + R3 border + NCHW->NHWC ----------------
__global__ __launch_bounds__(256) void k_prep(
    const float* __restrict__ x,
    const float* __restrict__ w_in, const float* __restrict__ w_out,
    const float* __restrict__ conv1_w, const float* __restrict__ down_w,
    const float* __restrict__ w_off, const float* __restrict__ w_mask,
    const float* __restrict__ b_off, const float* __restrict__ b_mask,
    __hip_bfloat16* __restrict__ w_inT, __hip_bfloat16* __restrict__ w_outT,
    __hip_bfloat16* __restrict__ c1T, __hip_bfloat16* __restrict__ dnT,
    __hip_bfloat16* __restrict__ w_omT, float* __restrict__ bias_om,
    float* __restrict__ stats, __hip_bfloat16* __restrict__ R3,
    __hip_bfloat16* __restrict__ xs)
{
  int b = blockIdx.x;
  if (b < 160){
    __shared__ float tl[32][257];
    const float* W; __hip_bfloat16* WT; int Kd, kb;
    if (b < 8)      { W = w_in;    WT = w_inT;  Kd = 256;  kb = b; }
    else if (b <16) { W = w_out;   WT = w_outT; Kd = 256;  kb = b-8; }
    else if (b <88) { W = conv1_w; WT = c1T;    Kd = 2304; kb = b-16; }
    else            { W = down_w;  WT = dnT;    Kd = 2304; kb = b-88; }
    int k0 = kb*32;
    #pragma unroll
    for (int dk=0; dk<32; dk++) tl[dk][threadIdx.x] = W[(size_t)(k0+dk)*256 + threadIdx.x];
    __syncthreads();
    #pragma unroll
    for (int r=0; r<32; r++){
      int co = r*8 + (threadIdx.x>>5);
      int dk = threadIdx.x&31;
      WT[(size_t)co*Kd + k0 + dk] = __float2bfloat16(tl[dk][co]);
    }
  } else if (b < 416){
    int n = b - 160, k = threadIdx.x;
    float v = (n<144) ? w_off[(size_t)k*144 + n] : (n<216 ? w_mask[(size_t)k*72 + (n-144)] : 0.f);
    w_omT[(size_t)n*256 + k] = __float2bfloat16(v);
    if (k==0) bias_om[n] = (n<144) ? b_off[n] : (n<216 ? b_mask[n-144] : 0.f);
  } else if (b < 546){
    int gid = (b-416)*8 + (threadIdx.x>>5);
    if (gid >= 1040) return;
    int n = gid/260; int ci = gid - n*260;
    int r, c;
    if (ci < 66){ r = 0; c = ci; }
    else if (ci < 132){ r = 65; c = ci-66; }
    else { int q = ci-132; r = 1 + (q>>1); c = (q&1) ? 65 : 0; }
    uint4* p = (uint4*)(R3 + ((size_t)((n*66+r)*66+c))*256) + (threadIdx.x&31);
    *p = make_uint4(0,0,0,0);
  } else if (b == 546){
    stats[threadIdx.x] = 0.f;
    stats[256+threadIdx.x] = 0.f;
    stats[512+threadIdx.x] = 0.f;
  } else {
    // NCHW fp32 -> NHWC bf16 transpose, 32x32 tile
    __shared__ float tile[32][33];
    int t = b - 547;                 // 0..4095
    int n = t >> 10;
    int c0 = ((t >> 7) & 7) * 32;
    int hw0 = (t & 127) * 32;
    int tx = threadIdx.x & 31, ty = threadIdx.x >> 5;
    #pragma unroll
    for (int ii=0; ii<4; ii++){
      int ci = ty + ii*8;
      tile[ci][tx] = x[(size_t)(n*256 + c0+ci)*4096 + hw0 + tx];
    }
    __syncthreads();
    #pragma unroll
    for (int ii=0; ii<4; ii++){
      int hwi = ty + ii*8;
      xs[((size_t)n*4096 + hw0+hwi)*256 + c0 + tx] = __float2bfloat16(tile[tx][hwi]);
    }
  }
}

// ---------------- MFMA GEMM / implicit conv body, 3-buf counted-vmcnt pipeline ----------------
// AMODE 0: A=[M][KTOT] bf16. AMODE 1: A=(4,66,66,256) padded bf16, implicit 3x3, stride STRIDE.
// OMODE 0: bf16 [M][256]+bias. OMODE 1: bf16 padded +bias. OMODE 2: fp32 ldc=216 col<216.
template<int AMODE, int OMODE, int STRIDE, int KTOT, int NSHIFT, int NWG>
__device__ __forceinline__ void mm_body(int id,
    const __hip_bfloat16* __restrict__ A, const __hip_bfloat16* __restrict__ Bt,
    const float* __restrict__ bias, float* __restrict__ OF, __hip_bfloat16* __restrict__ OH,
    float* __restrict__ stats, char* ldsc)
{
  constexpr int AROWS = 64;
  constexpr int MI = 2;
  constexpr int WROWS = 32;
  constexpr int JA = 2;
  constexpr int BUFSZ = AROWS*128 + 16384;   // 24576
  const int tid = threadIdx.x;
  const int lane = tid & 63;
  const int wv = tid >> 6;
  const int wr = wv >> 1, wc = wv & 1;

  // XCD-chunked bijective swizzle (NWG % 8 == 0)
  int sw = (id & 7) * (NWG >> 3) + (id >> 3);
  const int m0 = (sw >> 1) * AROWS, n0 = (sw & 1) * 128;

  const int swz_s = ((tid >> 3) & 7) << 4;
  const int cby = ((tid & 7) << 4) ^ swz_s;
  const int kl = cby >> 1;
  int aoff[JA], boff[4];
  #pragma unroll
  for (int j=0;j<JA;j++){
    int row = j*32 + (tid>>3);
    if (AMODE==0){
      aoff[j] = (m0 + row) * KTOT + kl;
    } else {
      int m = m0 + row;
      int n, ho, wo;
      if (STRIDE==1){ n = m>>12; ho = (m>>6)&63; wo = m&63; }
      else          { n = m>>10; ho = (m>>5)&31; wo = m&31; }
      aoff[j] = ((n*66 + ho*STRIDE)*66 + wo*STRIDE)*256 + kl;
    }
  }
  #pragma unroll
  for (int j=0;j<4;j++) boff[j] = (n0 + j*32 + (tid>>3)) * KTOT + kl;
  char* ldsst = ldsc + wv*1024;

  const int fr = lane & 15;
  const int kb = (lane >> 4) << 4;
  const int swz_r = (fr & 7) << 4;
  int aRow[MI], bRow[4];
  #pragma unroll
  for (int i=0;i<MI;i++) aRow[i] = (wr*WROWS + i*16 + fr) * 128;
  #pragma unroll
  for (int i=0;i<4;i++)  bRow[i] = AROWS*128 + (wc*64 + i*16 + fr) * 128;
  int cb[2];
  cb[0] = kb ^ swz_r;
  cb[1] = (64 | kb) ^ swz_r;

  // bias loads FIRST so the vmcnt FIFO counts only stage loads after them
  float bn[4];
  #pragma unroll
  for (int ni=0;ni<4;ni++) bn[ni] = bias[n0 + wc*64 + ni*16 + fr];

  f32x4 acc[MI][4];
  #pragma unroll
  for (int mi=0;mi<MI;mi++)
    #pragma unroll
    for (int ni=0;ni<4;ni++)
      acc[mi][ni] = (f32x4){0.f,0.f,0.f,0.f};

  auto STAGE = [&](int buf, int t){
    const int k0 = t*64;
    int astep;
    if (AMODE==1){
      int tap = k0 >> 8;
      int kh = (tap>=6) ? 2 : (tap>=3 ? 1 : 0);
      int kw = tap - kh*3;
      astep = (kh*66 + kw)*256 + (k0 & 255);
    } else astep = k0;
    char* db = ldsst + buf*BUFSZ;
    #pragma unroll
    for (int j=0;j<JA;j++) gload16(A + aoff[j] + astep, db + j*4096);
    #pragma unroll
    for (int j=0;j<4;j++)  gload16(Bt + boff[j] + k0, db + AROWS*128 + j*4096);
  };

  constexpr int NT = KTOT / 64;             // >= 4 for all instantiations
  STAGE(0, 0);
  STAGE(1, 1);
  WAITV(6);
  __builtin_amdgcn_s_barrier();
  __builtin_amdgcn_sched_barrier(0);
  for (int t=0; t<NT; ++t){
    if (t+2 < NT) STAGE((t+2)%3, t+2);
    char* cbase = ldsc + (t%3)*BUFSZ;
    __builtin_amdgcn_s_setprio(1);
    #pragma unroll
    for (int kk=0; kk<2; kk++){
      bf16x8 av[MI], bv[4];
      #pragma unroll
      for (int i=0;i<MI;i++) av[i] = *(const bf16x8*)(cbase + aRow[i] + cb[kk]);
      #pragma unroll
      for (int i=0;i<4;i++)  bv[i] = *(const bf16x8*)(cbase + bRow[i] + cb[kk]);
      #pragma unroll
      for (int mi=0;mi<MI;mi++)
        #pragma unroll
        for (int ni=0;ni<4;ni++)
          acc[mi][ni] = __builtin_amdgcn_mfma_f32_16x16x32_bf16(av[mi], bv[ni], acc[mi][ni], 0,0,0);
    }
    __builtin_amdgcn_s_setprio(0);
    if (t < NT-1){
      if (t+2 < NT){ WAITV(6); }
      else WAITV(0);
      __builtin_amdgcn_s_barrier();
      __builtin_amdgcn_sched_barrier(0);
    }
  }

  float sni[4] = {0.f,0.f,0.f,0.f};
  float qni[4] = {0.f,0.f,0.f,0.f};
  #pragma unroll
  for (int mi=0;mi<MI;mi++){
    #pragma unroll
    for (int r=0;r<4;r++){
      int gr = m0 + wr*WROWS + mi*16 + (lane>>4)*4 + r;
      #pragma unroll
      for (int ni=0;ni<4;ni++){
        int gc = n0 + wc*64 + ni*16 + fr;
        float v = acc[mi][ni][r] + bn[ni];
        if (NSHIFT){ sni[ni] += v; qni[ni] += v*v; }
        if (OMODE==0){
          OH[(size_t)gr*256 + gc] = __float2bfloat16(v);
        } else if (OMODE==1){
          int n = gr>>12, h = (gr>>6)&63, w = gr&63;
          OH[((size_t)((n*66)+(h+1))*66 + (w+1))*256 + gc] = __float2bfloat16(v);
        } else {
          if (gc < 216) OF[(size_t)gr*216 + gc] = v;
        }
      }
    }
  }
  if (NSHIFT){
    #pragma unroll
    for (int ni=0;ni<4;ni++){
      #pragma unroll
      for (int msk=16; msk<64; msk<<=1){
        sni[ni] += __shfl_xor(sni[ni], msk);
        qni[ni] += __shfl_xor(qni[ni], msk);
      }
      #pragma unroll
      for (int msk=1; msk<8; msk<<=1){
        sni[ni] += __shfl_xor(sni[ni], msk);
        qni[ni] += __shfl_xor(qni[ni], msk);
      }
    }
    __syncthreads();                 // all waves out of K-loop before LDS reuse
    float* ls = (float*)ldsc;
    if (tid < 32) ls[tid] = 0.f;
    __syncthreads();
    if ((lane & 7) == 0 && (lane & 48) == 0){
      int oct = (lane>>3) & 1;
      #pragma unroll
      for (int ni=0;ni<4;ni++){
        int idx = wc*8 + ni*2 + oct;
        atomicAdd(&ls[idx], sni[ni]);
        atomicAdd(&ls[16+idx], qni[ni]);
      }
    }
    __syncthreads();
    if (tid < 16){
      int gg = (m0>>NSHIFT)*32 + (n0>>3) + tid;
      atomicAdd(&stats[gg*2+0], ls[tid]);
      atomicAdd(&stats[gg*2+1], ls[16+tid]);
    }
  }
}

// ---------------- k_mm standalone wrapper ----------------
template<int AMODE, int OMODE, int STRIDE, int KTOT, int NSHIFT, int NWG>
__global__ __launch_bounds__(256) void k_mm(
    const __hip_bfloat16* __restrict__ A, const __hip_bfloat16* __restrict__ Bt,
    const float* __restrict__ bias, float* __restrict__ OF, __hip_bfloat16* __restrict__ OH,
    float* __restrict__ stats)
{
  __shared__ __align__(16) char SMEM[73728];
  int id = blockIdx.y * gridDim.x + blockIdx.x;
  mm_body<AMODE,OMODE,STRIDE,KTOT,NSHIFT,NWG>(id, A, Bt, bias, OF, OH, stats, SMEM);
}

// ---------------- depthwise conv 3x3 + LayerNorm + GELU unit ----------------
__device__ __forceinline__ void dwln_unit(int l, const __hip_bfloat16* __restrict__ xs,
    const float* lw, const float* lb, const float* lg, const float* lbt,
    __hip_bfloat16* __restrict__ t)
{
  int tid = threadIdx.x;
  int posl = tid>>5, cg = tid&31, c0 = cg*8;
  int pos = l*8 + posl;
  int nb = pos>>12, h = (pos>>6)&63, w = pos&63;
  float v[8];
  #pragma unroll
  for (int k=0;k<8;k++) v[k] = lb[c0+k];
  #pragma unroll
  for (int kh=0;kh<3;kh++){
    int hin = h+kh-1;
    if (hin<0||hin>=64) continue;
    #pragma unroll
    for (int kw=0;kw<3;kw++){
      int win = w+kw-1;
      if (win<0||win>=64) continue;
      const unsigned short* xr = (const unsigned short*)xs + ((size_t)((nb*64+hin)*64+win))*256 + c0;
      uint4 u = *(const uint4*)xr;
      const float* wr = &lw[(kh*3+kw)*256 + c0];
      v[0] += blo(u.x)*wr[0]; v[1] += bhi(u.x)*wr[1];
      v[2] += blo(u.y)*wr[2]; v[3] += bhi(u.y)*wr[3];
      v[4] += blo(u.z)*wr[4]; v[5] += bhi(u.z)*wr[5];
      v[6] += blo(u.w)*wr[6]; v[7] += bhi(u.w)*wr[7];
    }
  }
  float s=0.f, s2=0.f;
  #pragma unroll
  for (int k=0;k<8;k++){ s += v[k]; s2 += v[k]*v[k]; }
  #pragma unroll
  for (int m=1;m<32;m<<=1){ s += __shfl_xor(s,m); s2 += __shfl_xor(s2,m); }
  float mu = s*(1.f/256.f);
  float var = s2*(1.f/256.f) - mu*mu;
  float rstd = rsqrtf(var + 1e-5f);
  float ge[8];
  #pragma unroll
  for (int k=0;k<8;k++){
    float xn = (v[k]-mu)*rstd*lg[c0+k] + lbt[c0+k];
    ge[k] = 0.5f*xn*(1.f + erff(xn*0.70710678118654752f));
  }
  uint4 o;
  o.x = pk2(ge[0],ge[1]); o.y = pk2(ge[2],ge[3]);
  o.z = pk2(ge[4],ge[5]); o.w = pk2(ge[6],ge[7]);
  *(uint4*)((unsigned short*)t + (size_t)pos*256 + c0) = o;
}

// ---------------- fused P1: input_proj GEMM (blocks 0..511) ∥ dwln (blocks 512..2559) ----------------
__global__ __launch_bounds__(256) void k_p1(
    const __hip_bfloat16* __restrict__ xs, const __hip_bfloat16* __restrict__ w_inT,
    const float* __restrict__ b_in, __hip_bfloat16* __restrict__ R3,
    const float* __restrict__ dw_w, const float* __restrict__ dw_b,
    const float* __restrict__ ln_g, const float* __restrict__ ln_b,
    __hip_bfloat16* __restrict__ t)
{
  __shared__ __align__(16) char SMEM[73728];
  int bid = blockIdx.x;
  if (bid < 512){
    mm_body<0,1,1,256,0,512>(bid, xs, w_inT, b_in, nullptr, R3, nullptr, SMEM);
  } else {
    float* lw = (float*)SMEM;
    float* lb = (float*)(SMEM+9216);
    float* lg = (float*)(SMEM+10240);
    float* lbt= (float*)(SMEM+11264);
    int tid = threadIdx.x;
    #pragma unroll
    for (int p=0;p<9;p++) lw[p*256+tid] = dw_w[p*256+tid];
    lb[tid] = dw_b[tid]; lg[tid] = ln_g[tid]; lbt[tid] = ln_b[tid];
    __syncthreads();
    dwln_unit(bid-512, xs, lw, lb, lg, lbt, t);
  }
}

// ---------------- DCNv3 sampling: D staged in LDS, 8ch/lane, fused softmax ----------------
__global__ __launch_bounds__(256) void k_sample(
    const __hip_bfloat16* __restrict__ xp, const float* __restrict__ D, __hip_bfloat16* __restrict__ y)
{
  __shared__ float Ds[1728];        // 8 positions x 216
  int tid = threadIdx.x;
  {
    float4* dst = (float4*)Ds;
    const float4* src = (const float4*)(D + (size_t)blockIdx.x*1728);
    if (tid < 216){ dst[tid] = src[tid]; dst[tid+216] = src[tid+216]; }
    __syncthreads();
  }
  int pp = tid>>5;
  int g = (tid>>2)&7, li = tid&3;
  int pos = blockIdx.x*8 + pp;
  int nb = pos >> 12, h = (pos >> 6) & 63, w = pos & 63;
  const float* offp = Ds + pp*216 + g*18;
  const float* mskp = Ds + pp*216 + 144 + g*9;
  float mr[9];
  #pragma unroll
  for (int p=0;p<9;p++) mr[p] = mskp[p];
  float mx = mr[0];
  #pragma unroll
  for (int p=1;p<9;p++) mx = fmaxf(mx, mr[p]);
  float ssum = 0.f;
  #pragma unroll
  for (int p=0;p<9;p++){ mr[p] = __expf(mr[p]-mx); ssum += mr[p]; }
  float rinv = 1.f/ssum;
  const unsigned short* img = (const unsigned short*)xp + (size_t)nb*4356*256 + g*32 + li*8;
  float a0=0,a1=0,a2=0,a3=0,a4=0,a5=0,a6=0,a7=0;
  #pragma unroll
  for (int p=0;p<9;p++){
    int di = p/3 - 1, dj = p%3 - 1;
    float ox = offp[p*2], oy = offp[p*2+1];
    float px = (float)(w + 1 + di) + ox;
    float py = (float)(h + 1 + dj) + oy;
    float x0f = floorf(px), y0f = floorf(py);
    float wx1 = px - x0f, wy1 = py - y0f;
    float wx0 = 1.f - wx1, wy0 = 1.f - wy1;
    int x0 = (int)x0f, y0 = (int)y0f;
    float s0=0,s1=0,s2=0,s3=0,s4=0,s5=0,s6=0,s7=0;
    #pragma unroll
    for (int cy=0;cy<2;cy++){
      int yi = y0+cy;
      if (yi<0||yi>=66) continue;
      float wy = cy ? wy1 : wy0;
      #pragma unroll
      for (int cx=0;cx<2;cx++){
        int xi = x0+cx;
        if (xi<0||xi>=66) continue;
        float wq = (cx ? wx1 : wx0)*wy;
        uint4 u = *(const uint4*)(img + (size_t)(yi*66+xi)*256);
        s0 += blo(u.x)*wq; s1 += bhi(u.x)*wq;
        s2 += blo(u.y)*wq; s3 += bhi(u.y)*wq;
        s4 += blo(u.z)*wq; s5 += bhi(u.z)*wq;
        s6 += blo(u.w)*wq; s7 += bhi(u.w)*wq;
      }
    }
    float mp = mr[p]*rinv;
    a0 += s0*mp; a1 += s1*mp; a2 += s2*mp; a3 += s3*mp;
    a4 += s4*mp; a5 += s5*mp; a6 += s6*mp; a7 += s7*mp;
  }
  uint4 o;
  o.x = pk2(a0,a1); o.y = pk2(a2,a3); o.z = pk2(a4,a5); o.w = pk2(a6,a7);
  *(uint4*)((unsigned short*)y + (size_t)pos*256 + g*32 + li*8) = o;
}

// ---------------- GN apply + SiLU -> padded bf16 (+border), 8ch/thread, bf16 in ----------------
__global__ __launch_bounds__(256) void k_gnapply(
    const __hip_bfloat16* __restrict__ X, const float* __restrict__ stats,
    const float* __restrict__ gamma, const float* __restrict__ beta,
    __hip_bfloat16* __restrict__ OH, int nmain)
{
  int b = blockIdx.x;
  int tid = threadIdx.x;
  if (b >= nmain){
    int gid = (b - nmain)*8 + (tid>>5);
    if (gid >= 1040) return;
    int n = gid/260; int ci = gid - n*260;
    int r, c;
    if (ci < 66){ r = 0; c = ci; }
    else if (ci < 132){ r = 65; c = ci-66; }
    else { int q = ci-132; r = 1 + (q>>1); c = (q&1) ? 65 : 0; }
    uint4* p = (uint4*)(OH + ((size_t)((n*66+r)*66+c))*256) + (tid&31);
    *p = make_uint4(0,0,0,0);
    return;
  }
  int row = b*8 + (tid>>5);
  int grp = tid & 31;
  int c0 = grp*8;
  int nb = row >> 12;
  float S  = stats[(nb*32+grp)*2+0];
  float S2 = stats[(nb*32+grp)*2+1];
  const float inv = 1.f/32768.f;
  float mu = S*inv;
  float rs = rsqrtf(S2*inv - mu*mu + 1e-5f);
  float4 g0 = *(const float4*)(gamma + c0), g1 = *(const float4*)(gamma + c0 + 4);
  float4 bt0 = *(const float4*)(beta + c0), bt1 = *(const float4*)(beta + c0 + 4);
  uint4 u = *(const uint4*)((const unsigned short*)X + (size_t)row*256 + c0);
  float v[8] = { blo(u.x), bhi(u.x), blo(u.y), bhi(u.y), blo(u.z), bhi(u.z), blo(u.w), bhi(u.w) };
  float gm[8] = { g0.x,g0.y,g0.z,g0.w,g1.x,g1.y,g1.z,g1.w };
  float bb[8] = { bt0.x,bt0.y,bt0.z,bt0.w,bt1.x,bt1.y,bt1.z,bt1.w };
  #pragma unroll
  for (int k=0;k<8;k++){
    float t = (v[k]-mu)*rs*gm[k] + bb[k];
    v[k] = t / (1.f + expf(-t));
  }
  int h = (row>>6)&63, w = row&63;
  uint4 o;
  o.x = pk2(v[0],v[1]); o.y = pk2(v[2],v[3]); o.z = pk2(v[4],v[5]); o.w = pk2(v[6],v[7]);
  *(uint4*)((unsigned short*)OH + ((size_t)((nb*66)+(h+1))*66 + (w+1))*256 + c0) = o;
}

// ---------------- GN3 apply -> fp32 NCHW out, LDS transpose for coalesced write ----------------
__global__ __launch_bounds__(256) void k_gnout(
    const __hip_bfloat16* __restrict__ X, const float* __restrict__ stats,
    const float* __restrict__ gamma, const float* __restrict__ beta, float* __restrict__ out)
{
  __shared__ float val[8][1024];
  int nb = blockIdx.x >> 5, cg = blockIdx.x & 31;
  int c0 = cg*8;
  float S  = stats[(nb*32+cg)*2+0];
  float S2 = stats[(nb*32+cg)*2+1];
  const float inv = 1.f/8192.f;
  float mu = S*inv;
  float rs = rsqrtf(S2*inv - mu*mu + 1e-5f);
  float4 g0 = *(const float4*)(gamma + c0), g1 = *(const float4*)(gamma + c0 + 4);
  float4 bt0 = *(const float4*)(beta + c0), bt1 = *(const float4*)(beta + c0 + 4);
  float gm[8] = { g0.x,g0.y,g0.z,g0.w,g1.x,g1.y,g1.z,g1.w };
  float bb[8] = { bt0.x,bt0.y,bt0.z,bt0.w,bt1.x,bt1.y,bt1.z,bt1.w };
  #pragma unroll
  for (int k=0;k<4;k++){
    int pos = k*256 + threadIdx.x;
    uint4 u = *(const uint4*)((const unsigned short*)X + ((size_t)(nb*1024+pos))*256 + c0);
    float v[8] = { blo(u.x), bhi(u.x), blo(u.y), bhi(u.y), blo(u.z), bhi(u.z), blo(u.w), bhi(u.w) };
    #pragma unroll
    for (int q=0;q<8;q++) val[q][pos] = (v[q]-mu)*rs*gm[q] + bb[q];
  }
  __syncthreads();
  int ch = threadIdx.x>>5, pl = threadIdx.x&31;
  float* orow = out + (((size_t)(nb*256 + c0 + ch))<<10);
  #pragma unroll
  for (int j=0;j<32;j++) orow[pl + j*32] = val[ch][pl + j*32];
}

extern "C" void kernel_launch(void* const* d_in, const int* in_sizes, int n_in,
                              void* d_out, int out_size, void* d_ws, size_t ws_size,
                              hipStream_t stream) {
  const float* x      = (const float*)d_in[0];
  const float* w_in   = (const float*)d_in[1];
  const float* b_in   = (const float*)d_in[2];
  const float* dw_w   = (const float*)d_in[3];
  const float* dw_b   = (const float*)d_in[4];
  const float* ln_g   = (const float*)d_in[5];
  const float* ln_b   = (const float*)d_in[6];
  const float* w_off  = (const float*)d_in[7];
  const float* b_off  = (const float*)d_in[8];
  const float* w_mask = (const float*)d_in[9];
  const float* b_mask = (const float*)d_in[10];
  const float* w_out  = (const float*)d_in[11];
  const float* b_out  = (const float*)d_in[12];
  const float* gn1_g  = (const float*)d_in[13];
  const float* gn1_b  = (const float*)d_in[14];
  const float* conv1_w= (const float*)d_in[15];
  const float* conv1_b= (const float*)d_in[16];
  const float* gn2_g  = (const float*)d_in[17];
  const float* gn2_b  = (const float*)d_in[18];
  const float* down_w = (const float*)d_in[19];
  const float* down_b = (const float*)d_in[20];
  const float* gn3_g  = (const float*)d_in[21];
  const float* gn3_b  = (const float*)d_in[22];
  float* out = (float*)d_out;

  char* wsb = (char*)d_ws;
  __hip_bfloat16* R0h = (__hip_bfloat16*)wsb;             // 8 MB bf16 (y2 / down-out)
  float* R1f = (float*)(wsb + 16777216);                  // fp32 offmask / bf16 conv1-out
  __hip_bfloat16* R1h = (__hip_bfloat16*)(wsb + 16777216);
  __hip_bfloat16* R2 = (__hip_bfloat16*)(wsb + 33554432); // 8 MB bf16 (xs -> agg)
  __hip_bfloat16* R3 = (__hip_bfloat16*)(wsb + 41943040); // 8.92 MB bf16 (xp -> gn2pad)
  __hip_bfloat16* R4 = (__hip_bfloat16*)(wsb + 50864128); // 8.92 MB bf16 (t -> gn1pad)
  char* R5 = wsb + 59785216;
  __hip_bfloat16* w_inT  = (__hip_bfloat16*)R5;
  __hip_bfloat16* w_outT = (__hip_bfloat16*)(R5 + 131072);
  __hip_bfloat16* w_omT  = (__hip_bfloat16*)(R5 + 262144);
  __hip_bfloat16* c1T    = (__hip_bfloat16*)(R5 + 393216);
  __hip_bfloat16* dnT    = (__hip_bfloat16*)(R5 + 1572864);
  float* bias_om         = (float*)(R5 + 2752512);
  float* stats           = (float*)(R5 + 2753536);        // 768 floats: GN1|GN2|GN3

  // 0. fused prep (weights, offmask, R3 border, stats zero, NCHW->NHWC)
  k_prep<<<4643, 256, 0, stream>>>(x, w_in, w_out, conv1_w, down_w, w_off, w_mask, b_off, b_mask,
                                   w_inT, w_outT, c1T, dnT, w_omT, bias_om, stats, R3, R2);
  // 1. input_proj (-> padded R3)  ∥  depthwise+LN+GELU (-> R4)
  k_p1<<<2560, 256, 0, stream>>>(R2, w_inT, b_in, R3, dw_w, dw_b, ln_g, ln_b, R4);
  // 2. fused offset+mask GEMM -> R1 fp32
  k_mm<0,2,1,256,0,512><<<dim3(256,2), 256, 0, stream>>>(R4, w_omT, bias_om, R1f, nullptr, nullptr);
  // 3. sample -> agg (R2)
  k_sample<<<2048, 256, 0, stream>>>(R3, R1f, R2);
  // 4. output_proj -> R0 bf16 + GN1 stats
  k_mm<0,0,1,256,12,512><<<dim3(256,2), 256, 0, stream>>>(R2, w_outT, b_out, nullptr, R0h, stats);
  // 5. GN1 + SiLU -> padded bf16 (R4) + border
  k_gnapply<<<2048+130, 256, 0, stream>>>(R0h, stats, gn1_g, gn1_b, R4, 2048);
  // 6. conv1 -> R1 bf16 + GN2 stats
  k_mm<1,0,1,2304,12,512><<<dim3(256,2), 256, 0, stream>>>(R4, c1T, conv1_b, nullptr, R1h, stats+256);
  // 7. GN2 + SiLU -> padded bf16 (R3) + border
  k_gnapply<<<2048+130, 256, 0, stream>>>(R1h, stats+256, gn2_g, gn2_b, R3, 2048);
  // 8. down conv stride 2 -> R0 bf16 + GN3 stats
  k_mm<1,0,2,2304,10,128><<<dim3(64,2), 256, 0, stream>>>(R3, dnT, down_b, nullptr, R0h, stats+512);
  // 9. GN3 -> out NCHW fp32 (coalesced via LDS transpose)
  k_gnout<<<128, 256, 0, stream>>>(R0h, stats+512, gn3_g, gn3_b, out);
}

// Round 9
// 236.144 us; speedup vs baseline: 2.8497x; 1.0354x over previous
//
#include <hip/hip_runtime.h>
#include <hip/hip_bf16.h>
#include <math.h>

// N=4, H=W=64, C=256, G=8, GC=32, K=3, P=9, pad=1. Padded spatial: 66x66.

typedef __attribute__((ext_vector_type(8))) short bf16x8;
typedef __attribute__((ext_vector_type(4))) float f32x4;

__device__ __forceinline__ float blo(unsigned u){
  union { unsigned int i; float f; } v; v.i = u<<16; return v.f;
}
__device__ __forceinline__ float bhi(unsigned u){
  union { unsigned int i; float f; } v; v.i = u & 0xffff0000u; return v.f;
}
__device__ __forceinline__ unsigned short f2b(float f){
  __hip_bfloat16 h = __float2bfloat16(f);
  return *reinterpret_cast<unsigned short*>(&h);
}
__device__ __forceinline__ unsigned pk2(float lo, float hi){
  return (unsigned)f2b(lo) | ((unsigned)f2b(hi)<<16);
}

__device__ __forceinline__ void gload16(const void* g, void* l){
  auto gp = reinterpret_cast<const __attribute__((address_space(1))) unsigned*>(
      reinterpret_cast<uintptr_t>(g));
  auto lp = reinterpret_cast<__attribute__((address_space(3))) unsigned*>(
      reinterpret_cast<uintptr_t>(l));
  __builtin_amdgcn_global_load_lds(gp, lp, 16, 0, 0);
}

#define WAITV(n) asm volatile("s_waitcnt vmcnt(" #n ")" ::: "memory")

// ---------------- fused prep: weight transposes + offmask + stats zero + R3 border + NCHW->NHWC ----------------
__global__ __launch_bounds__(256) void k_prep(
    const float* __restrict__ x,
    const float* __restrict__ w_in, const float* __restrict__ w_out,
    const float* __restrict__ conv1_w, const float* __restrict__ down_w,
    const float* __restrict__ w_off, const float* __restrict__ w_mask,
    const float* __restrict__ b_off, const float* __restrict__ b_mask,
    __hip_bfloat16* __restrict__ w_inT, __hip_bfloat16* __restrict__ w_outT,
    __hip_bfloat16* __restrict__ c1T, __hip_bfloat16* __restrict__ dnT,
    __hip_bfloat16* __restrict__ w_omT, float* __restrict__ bias_om,
    float* __restrict__ stats, __hip_bfloat16* __restrict__ R3,
    __hip_bfloat16* __restrict__ xs)
{
  int b = blockIdx.x;
  if (b < 160){
    __shared__ float tl[32][257];
    const float* W; __hip_bfloat16* WT; int Kd, kb;
    if (b < 8)      { W = w_in;    WT = w_inT;  Kd = 256;  kb = b; }
    else if (b <16) { W = w_out;   WT = w_outT; Kd = 256;  kb = b-8; }
    else if (b <88) { W = conv1_w; WT = c1T;    Kd = 2304; kb = b-16; }
    else            { W = down_w;  WT = dnT;    Kd = 2304; kb = b-88; }
    int k0 = kb*32;
    #pragma unroll
    for (int dk=0; dk<32; dk++) tl[dk][threadIdx.x] = W[(size_t)(k0+dk)*256 + threadIdx.x];
    __syncthreads();
    #pragma unroll
    for (int r=0; r<32; r++){
      int co = r*8 + (threadIdx.x>>5);
      int dk = threadIdx.x&31;
      WT[(size_t)co*Kd + k0 + dk] = __float2bfloat16(tl[dk][co]);
    }
  } else if (b < 416){
    int n = b - 160, k = threadIdx.x;
    float v = (n<144) ? w_off[(size_t)k*144 + n] : (n<216 ? w_mask[(size_t)k*72 + (n-144)] : 0.f);
    w_omT[(size_t)n*256 + k] = __float2bfloat16(v);
    if (k==0) bias_om[n] = (n<144) ? b_off[n] : (n<216 ? b_mask[n-144] : 0.f);
  } else if (b < 546){
    int gid = (b-416)*8 + (threadIdx.x>>5);
    if (gid >= 1040) return;
    int n = gid/260; int ci = gid - n*260;
    int r, c;
    if (ci < 66){ r = 0; c = ci; }
    else if (ci < 132){ r = 65; c = ci-66; }
    else { int q = ci-132; r = 1 + (q>>1); c = (q&1) ? 65 : 0; }
    uint4* p = (uint4*)(R3 + ((size_t)((n*66+r)*66+c))*256) + (threadIdx.x&31);
    *p = make_uint4(0,0,0,0);
  } else if (b == 546){
    stats[threadIdx.x] = 0.f;
    stats[256+threadIdx.x] = 0.f;
    stats[512+threadIdx.x] = 0.f;
  } else {
    // NCHW fp32 -> NHWC bf16 transpose, 32x32 tile
    __shared__ float tile[32][33];
    int t = b - 547;                 // 0..4095
    int n = t >> 10;
    int c0 = ((t >> 7) & 7) * 32;
    int hw0 = (t & 127) * 32;
    int tx = threadIdx.x & 31, ty = threadIdx.x >> 5;
    #pragma unroll
    for (int ii=0; ii<4; ii++){
      int ci = ty + ii*8;
      tile[ci][tx] = x[(size_t)(n*256 + c0+ci)*4096 + hw0 + tx];
    }
    __syncthreads();
    #pragma unroll
    for (int ii=0; ii<4; ii++){
      int hwi = ty + ii*8;
      xs[((size_t)n*4096 + hw0+hwi)*256 + c0 + tx] = __float2bfloat16(tile[tx][hwi]);
    }
  }
}

// ---------------- MFMA GEMM / implicit conv, 64-row tiles, 3-buf counted-vmcnt pipeline ----------------
// AMODE 0: A=[M][KTOT] bf16. AMODE 1: A=(4,66,66,256) padded bf16, implicit 3x3, stride STRIDE.
// OMODE 0: bf16 [M][256]+bias. OMODE 1: bf16 padded +bias. OMODE 2: fp32 ldc=216 col<216.
// NSHIFT>0: accumulate per-(batch,group) sum/sumsq into stats.
template<int AMODE, int OMODE, int STRIDE, int KTOT, int NSHIFT>
__global__ __launch_bounds__(256) void k_mm(
    const __hip_bfloat16* __restrict__ A, const __hip_bfloat16* __restrict__ Bt,
    const float* __restrict__ bias, float* __restrict__ OF, __hip_bfloat16* __restrict__ OH,
    float* __restrict__ stats)
{
  constexpr int AROWS = 64;
  constexpr int MI = 2;
  constexpr int WROWS = 32;
  constexpr int JA = 2;
  constexpr int BUFSZ = AROWS*128 + 16384;   // 24576
  __shared__ uint4 lds4[3*BUFSZ/16];          // 72 KB, 3 buffers
  char* ldsc = (char*)lds4;
  const int tid = threadIdx.x;
  const int lane = tid & 63;
  const int wv = tid >> 6;
  const int wr = wv >> 1, wc = wv & 1;

  // XCD-chunked bijective swizzle (nwg % 8 == 0 for all launches)
  int id = blockIdx.y * gridDim.x + blockIdx.x;
  int cpx = (gridDim.x * gridDim.y) >> 3;
  int sw = (id & 7) * cpx + (id >> 3);
  const int m0 = (sw >> 1) * AROWS, n0 = (sw & 1) * 128;

  const int swz_s = ((tid >> 3) & 7) << 4;
  const int cby = ((tid & 7) << 4) ^ swz_s;
  const int kl = cby >> 1;
  int aoff[JA], boff[4];
  #pragma unroll
  for (int j=0;j<JA;j++){
    int row = j*32 + (tid>>3);
    if (AMODE==0){
      aoff[j] = (m0 + row) * KTOT + kl;
    } else {
      int m = m0 + row;
      int n, ho, wo;
      if (STRIDE==1){ n = m>>12; ho = (m>>6)&63; wo = m&63; }
      else          { n = m>>10; ho = (m>>5)&31; wo = m&31; }
      aoff[j] = ((n*66 + ho*STRIDE)*66 + wo*STRIDE)*256 + kl;
    }
  }
  #pragma unroll
  for (int j=0;j<4;j++) boff[j] = (n0 + j*32 + (tid>>3)) * KTOT + kl;
  char* ldsst = ldsc + wv*1024;

  const int fr = lane & 15;
  const int kb = (lane >> 4) << 4;
  const int swz_r = (fr & 7) << 4;
  int aRow[MI], bRow[4];
  #pragma unroll
  for (int i=0;i<MI;i++) aRow[i] = (wr*WROWS + i*16 + fr) * 128;
  #pragma unroll
  for (int i=0;i<4;i++)  bRow[i] = AROWS*128 + (wc*64 + i*16 + fr) * 128;
  int cb[2];
  cb[0] = kb ^ swz_r;
  cb[1] = (64 | kb) ^ swz_r;

  // bias loads FIRST so the vmcnt FIFO counts only stage loads after them
  float bn[4];
  #pragma unroll
  for (int ni=0;ni<4;ni++) bn[ni] = bias[n0 + wc*64 + ni*16 + fr];

  f32x4 acc[MI][4];
  #pragma unroll
  for (int mi=0;mi<MI;mi++)
    #pragma unroll
    for (int ni=0;ni<4;ni++)
      acc[mi][ni] = (f32x4){0.f,0.f,0.f,0.f};

  auto STAGE = [&](int buf, int t){
    const int k0 = t*64;
    int astep;
    if (AMODE==1){
      int tap = k0 >> 8;
      int kh = (tap>=6) ? 2 : (tap>=3 ? 1 : 0);
      int kw = tap - kh*3;
      astep = (kh*66 + kw)*256 + (k0 & 255);
    } else astep = k0;
    char* db = ldsst + buf*BUFSZ;
    #pragma unroll
    for (int j=0;j<JA;j++) gload16(A + aoff[j] + astep, db + j*4096);
    #pragma unroll
    for (int j=0;j<4;j++)  gload16(Bt + boff[j] + k0, db + AROWS*128 + j*4096);
  };

  constexpr int NT = KTOT / 64;             // >= 4 for all instantiations
  STAGE(0, 0);
  STAGE(1, 1);
  WAITV(6);
  __builtin_amdgcn_s_barrier();
  __builtin_amdgcn_sched_barrier(0);
  for (int t=0; t<NT; ++t){
    if (t+2 < NT) STAGE((t+2)%3, t+2);
    char* cbase = ldsc + (t%3)*BUFSZ;
    __builtin_amdgcn_s_setprio(1);
    #pragma unroll
    for (int kk=0; kk<2; kk++){
      bf16x8 av[MI], bv[4];
      #pragma unroll
      for (int i=0;i<MI;i++) av[i] = *(const bf16x8*)(cbase + aRow[i] + cb[kk]);
      #pragma unroll
      for (int i=0;i<4;i++)  bv[i] = *(const bf16x8*)(cbase + bRow[i] + cb[kk]);
      #pragma unroll
      for (int mi=0;mi<MI;mi++)
        #pragma unroll
        for (int ni=0;ni<4;ni++)
          acc[mi][ni] = __builtin_amdgcn_mfma_f32_16x16x32_bf16(av[mi], bv[ni], acc[mi][ni], 0,0,0);
    }
    __builtin_amdgcn_s_setprio(0);
    if (t < NT-1){
      if (t+2 < NT){ WAITV(6); }
      else WAITV(0);
      __builtin_amdgcn_s_barrier();
      __builtin_amdgcn_sched_barrier(0);
    }
  }

  float sni[4] = {0.f,0.f,0.f,0.f};
  float qni[4] = {0.f,0.f,0.f,0.f};
  #pragma unroll
  for (int mi=0;mi<MI;mi++){
    #pragma unroll
    for (int r=0;r<4;r++){
      int gr = m0 + wr*WROWS + mi*16 + (lane>>4)*4 + r;
      #pragma unroll
      for (int ni=0;ni<4;ni++){
        int gc = n0 + wc*64 + ni*16 + fr;
        float v = acc[mi][ni][r] + bn[ni];
        if (NSHIFT){ sni[ni] += v; qni[ni] += v*v; }
        if (OMODE==0){
          OH[(size_t)gr*256 + gc] = __float2bfloat16(v);
        } else if (OMODE==1){
          int n = gr>>12, h = (gr>>6)&63, w = gr&63;
          OH[((size_t)((n*66)+(h+1))*66 + (w+1))*256 + gc] = __float2bfloat16(v);
        } else {
          if (gc < 216) OF[(size_t)gr*216 + gc] = v;
        }
      }
    }
  }
  if (NSHIFT){
    #pragma unroll
    for (int ni=0;ni<4;ni++){
      #pragma unroll
      for (int msk=16; msk<64; msk<<=1){
        sni[ni] += __shfl_xor(sni[ni], msk);
        qni[ni] += __shfl_xor(qni[ni], msk);
      }
      #pragma unroll
      for (int msk=1; msk<8; msk<<=1){
        sni[ni] += __shfl_xor(sni[ni], msk);
        qni[ni] += __shfl_xor(qni[ni], msk);
      }
    }
    __syncthreads();                 // all waves out of K-loop before LDS reuse
    float* ls = (float*)ldsc;
    if (tid < 32) ls[tid] = 0.f;
    __syncthreads();
    if ((lane & 7) == 0 && (lane & 48) == 0){
      int oct = (lane>>3) & 1;
      #pragma unroll
      for (int ni=0;ni<4;ni++){
        int idx = wc*8 + ni*2 + oct;
        atomicAdd(&ls[idx], sni[ni]);
        atomicAdd(&ls[16+idx], qni[ni]);
      }
    }
    __syncthreads();
    if (tid < 16){
      int gg = (m0>>NSHIFT)*32 + (n0>>3) + tid;
      atomicAdd(&stats[gg*2+0], ls[tid]);
      atomicAdd(&stats[gg*2+1], ls[16+tid]);
    }
  }
}

// ---------------- depthwise conv 3x3 + LayerNorm + GELU, 8ch/thread, 16B loads ----------------
__global__ __launch_bounds__(256) void k_dwln(
    const __hip_bfloat16* __restrict__ xs, const float* __restrict__ dw_w, const float* __restrict__ dw_b,
    const float* __restrict__ ln_g, const float* __restrict__ ln_b, __hip_bfloat16* __restrict__ t)
{
  __shared__ float lw[9*256];
  __shared__ float lb[256], lg[256], lbt[256];
  int tid = threadIdx.x;
  #pragma unroll
  for (int p=0;p<9;p++) lw[p*256+tid] = dw_w[p*256+tid];
  lb[tid] = dw_b[tid]; lg[tid] = ln_g[tid]; lbt[tid] = ln_b[tid];
  __syncthreads();
  int posl = tid>>5, cg = tid&31, c0 = cg*8;
  int pos = blockIdx.x*8 + posl;
  int nb = pos>>12, h = (pos>>6)&63, w = pos&63;
  float v[8];
  #pragma unroll
  for (int k=0;k<8;k++) v[k] = lb[c0+k];
  #pragma unroll
  for (int kh=0;kh<3;kh++){
    int hin = h+kh-1;
    if (hin<0||hin>=64) continue;
    #pragma unroll
    for (int kw=0;kw<3;kw++){
      int win = w+kw-1;
      if (win<0||win>=64) continue;
      const unsigned short* xr = (const unsigned short*)xs + ((size_t)((nb*64+hin)*64+win))*256 + c0;
      uint4 u = *(const uint4*)xr;
      const float* wr = &lw[(kh*3+kw)*256 + c0];
      v[0] += blo(u.x)*wr[0]; v[1] += bhi(u.x)*wr[1];
      v[2] += blo(u.y)*wr[2]; v[3] += bhi(u.y)*wr[3];
      v[4] += blo(u.z)*wr[4]; v[5] += bhi(u.z)*wr[5];
      v[6] += blo(u.w)*wr[6]; v[7] += bhi(u.w)*wr[7];
    }
  }
  float s=0.f, s2=0.f;
  #pragma unroll
  for (int k=0;k<8;k++){ s += v[k]; s2 += v[k]*v[k]; }
  #pragma unroll
  for (int m=1;m<32;m<<=1){ s += __shfl_xor(s,m); s2 += __shfl_xor(s2,m); }
  float mu = s*(1.f/256.f);
  float var = s2*(1.f/256.f) - mu*mu;
  float rstd = rsqrtf(var + 1e-5f);
  float ge[8];
  #pragma unroll
  for (int k=0;k<8;k++){
    float xn = (v[k]-mu)*rstd*lg[c0+k] + lbt[c0+k];
    ge[k] = 0.5f*xn*(1.f + erff(xn*0.70710678118654752f));
  }
  uint4 o;
  o.x = pk2(ge[0],ge[1]); o.y = pk2(ge[2],ge[3]);
  o.z = pk2(ge[4],ge[5]); o.w = pk2(ge[6],ge[7]);
  *(uint4*)((unsigned short*)t + (size_t)pos*256 + c0) = o;
}

// ---------------- DCNv3 sampling: D staged in LDS, 8ch/lane, fused softmax ----------------
__global__ __launch_bounds__(256) void k_sample(
    const __hip_bfloat16* __restrict__ xp, const float* __restrict__ D, __hip_bfloat16* __restrict__ y)
{
  __shared__ float Ds[1728];        // 8 positions x 216
  int tid = threadIdx.x;
  {
    float4* dst = (float4*)Ds;
    const float4* src = (const float4*)(D + (size_t)blockIdx.x*1728);
    if (tid < 216){ dst[tid] = src[tid]; dst[tid+216] = src[tid+216]; }
    __syncthreads();
  }
  int pp = tid>>5;
  int g = (tid>>2)&7, li = tid&3;
  int pos = blockIdx.x*8 + pp;
  int nb = pos >> 12, h = (pos >> 6) & 63, w = pos & 63;
  const float* offp = Ds + pp*216 + g*18;
  const float* mskp = Ds + pp*216 + 144 + g*9;
  float mr[9];
  #pragma unroll
  for (int p=0;p<9;p++) mr[p] = mskp[p];
  float mx = mr[0];
  #pragma unroll
  for (int p=1;p<9;p++) mx = fmaxf(mx, mr[p]);
  float ssum = 0.f;
  #pragma unroll
  for (int p=0;p<9;p++){ mr[p] = __expf(mr[p]-mx); ssum += mr[p]; }
  float rinv = 1.f/ssum;
  const unsigned short* img = (const unsigned short*)xp + (size_t)nb*4356*256 + g*32 + li*8;
  float a0=0,a1=0,a2=0,a3=0,a4=0,a5=0,a6=0,a7=0;
  #pragma unroll
  for (int p=0;p<9;p++){
    int di = p/3 - 1, dj = p%3 - 1;
    float ox = offp[p*2], oy = offp[p*2+1];
    float px = (float)(w + 1 + di) + ox;
    float py = (float)(h + 1 + dj) + oy;
    float x0f = floorf(px), y0f = floorf(py);
    float wx1 = px - x0f, wy1 = py - y0f;
    float wx0 = 1.f - wx1, wy0 = 1.f - wy1;
    int x0 = (int)x0f, y0 = (int)y0f;
    float s0=0,s1=0,s2=0,s3=0,s4=0,s5=0,s6=0,s7=0;
    #pragma unroll
    for (int cy=0;cy<2;cy++){
      int yi = y0+cy;
      if (yi<0||yi>=66) continue;
      float wy = cy ? wy1 : wy0;
      #pragma unroll
      for (int cx=0;cx<2;cx++){
        int xi = x0+cx;
        if (xi<0||xi>=66) continue;
        float wq = (cx ? wx1 : wx0)*wy;
        uint4 u = *(const uint4*)(img + (size_t)(yi*66+xi)*256);
        s0 += blo(u.x)*wq; s1 += bhi(u.x)*wq;
        s2 += blo(u.y)*wq; s3 += bhi(u.y)*wq;
        s4 += blo(u.z)*wq; s5 += bhi(u.z)*wq;
        s6 += blo(u.w)*wq; s7 += bhi(u.w)*wq;
      }
    }
    float mp = mr[p]*rinv;
    a0 += s0*mp; a1 += s1*mp; a2 += s2*mp; a3 += s3*mp;
    a4 += s4*mp; a5 += s5*mp; a6 += s6*mp; a7 += s7*mp;
  }
  uint4 o;
  o.x = pk2(a0,a1); o.y = pk2(a2,a3); o.z = pk2(a4,a5); o.w = pk2(a6,a7);
  *(uint4*)((unsigned short*)y + (size_t)pos*256 + g*32 + li*8) = o;
}

// ---------------- GN apply + SiLU -> padded bf16 (+border), 8ch/thread, bf16 in ----------------
__global__ __launch_bounds__(256) void k_gnapply(
    const __hip_bfloat16* __restrict__ X, const float* __restrict__ stats,
    const float* __restrict__ gamma, const float* __restrict__ beta,
    __hip_bfloat16* __restrict__ OH, int nmain)
{
  int b = blockIdx.x;
  int tid = threadIdx.x;
  if (b >= nmain){
    int gid = (b - nmain)*8 + (tid>>5);
    if (gid >= 1040) return;
    int n = gid/260; int ci = gid - n*260;
    int r, c;
    if (ci < 66){ r = 0; c = ci; }
    else if (ci < 132){ r = 65; c = ci-66; }
    else { int q = ci-132; r = 1 + (q>>1); c = (q&1) ? 65 : 0; }
    uint4* p = (uint4*)(OH + ((size_t)((n*66+r)*66+c))*256) + (tid&31);
    *p = make_uint4(0,0,0,0);
    return;
  }
  int row = b*8 + (tid>>5);
  int grp = tid & 31;
  int c0 = grp*8;
  int nb = row >> 12;
  float S  = stats[(nb*32+grp)*2+0];
  float S2 = stats[(nb*32+grp)*2+1];
  const float inv = 1.f/32768.f;
  float mu = S*inv;
  float rs = rsqrtf(S2*inv - mu*mu + 1e-5f);
  float4 g0 = *(const float4*)(gamma + c0), g1 = *(const float4*)(gamma + c0 + 4);
  float4 bt0 = *(const float4*)(beta + c0), bt1 = *(const float4*)(beta + c0 + 4);
  uint4 u = *(const uint4*)((const unsigned short*)X + (size_t)row*256 + c0);
  float v[8] = { blo(u.x), bhi(u.x), blo(u.y), bhi(u.y), blo(u.z), bhi(u.z), blo(u.w), bhi(u.w) };
  float gm[8] = { g0.x,g0.y,g0.z,g0.w,g1.x,g1.y,g1.z,g1.w };
  float bb[8] = { bt0.x,bt0.y,bt0.z,bt0.w,bt1.x,bt1.y,bt1.z,bt1.w };
  #pragma unroll
  for (int k=0;k<8;k++){
    float t = (v[k]-mu)*rs*gm[k] + bb[k];
    v[k] = t / (1.f + expf(-t));
  }
  int h = (row>>6)&63, w = row&63;
  uint4 o;
  o.x = pk2(v[0],v[1]); o.y = pk2(v[2],v[3]); o.z = pk2(v[4],v[5]); o.w = pk2(v[6],v[7]);
  *(uint4*)((unsigned short*)OH + ((size_t)((nb*66)+(h+1))*66 + (w+1))*256 + c0) = o;
}

// ---------------- GN3 apply -> fp32 NCHW out, LDS transpose for coalesced write ----------------
__global__ __launch_bounds__(256) void k_gnout(
    const __hip_bfloat16* __restrict__ X, const float* __restrict__ stats,
    const float* __restrict__ gamma, const float* __restrict__ beta, float* __restrict__ out)
{
  __shared__ float val[8][1024];
  int nb = blockIdx.x >> 5, cg = blockIdx.x & 31;
  int c0 = cg*8;
  float S  = stats[(nb*32+cg)*2+0];
  float S2 = stats[(nb*32+cg)*2+1];
  const float inv = 1.f/8192.f;
  float mu = S*inv;
  float rs = rsqrtf(S2*inv - mu*mu + 1e-5f);
  float4 g0 = *(const float4*)(gamma + c0), g1 = *(const float4*)(gamma + c0 + 4);
  float4 bt0 = *(const float4*)(beta + c0), bt1 = *(const float4*)(beta + c0 + 4);
  float gm[8] = { g0.x,g0.y,g0.z,g0.w,g1.x,g1.y,g1.z,g1.w };
  float bb[8] = { bt0.x,bt0.y,bt0.z,bt0.w,bt1.x,bt1.y,bt1.z,bt1.w };
  #pragma unroll
  for (int k=0;k<4;k++){
    int pos = k*256 + threadIdx.x;
    uint4 u = *(const uint4*)((const unsigned short*)X + ((size_t)(nb*1024+pos))*256 + c0);
    float v[8] = { blo(u.x), bhi(u.x), blo(u.y), bhi(u.y), blo(u.z), bhi(u.z), blo(u.w), bhi(u.w) };
    #pragma unroll
    for (int q=0;q<8;q++) val[q][pos] = (v[q]-mu)*rs*gm[q] + bb[q];
  }
  __syncthreads();
  int ch = threadIdx.x>>5, pl = threadIdx.x&31;
  float* orow = out + (((size_t)(nb*256 + c0 + ch))<<10);
  #pragma unroll
  for (int j=0;j<32;j++) orow[pl + j*32] = val[ch][pl + j*32];
}

extern "C" void kernel_launch(void* const* d_in, const int* in_sizes, int n_in,
                              void* d_out, int out_size, void* d_ws, size_t ws_size,
                              hipStream_t stream) {
  const float* x      = (const float*)d_in[0];
  const float* w_in   = (const float*)d_in[1];
  const float* b_in   = (const float*)d_in[2];
  const float* dw_w   = (const float*)d_in[3];
  const float* dw_b   = (const float*)d_in[4];
  const float* ln_g   = (const float*)d_in[5];
  const float* ln_b   = (const float*)d_in[6];
  const float* w_off  = (const float*)d_in[7];
  const float* b_off  = (const float*)d_in[8];
  const float* w_mask = (const float*)d_in[9];
  const float* b_mask = (const float*)d_in[10];
  const float* w_out  = (const float*)d_in[11];
  const float* b_out  = (const float*)d_in[12];
  const float* gn1_g  = (const float*)d_in[13];
  const float* gn1_b  = (const float*)d_in[14];
  const float* conv1_w= (const float*)d_in[15];
  const float* conv1_b= (const float*)d_in[16];
  const float* gn2_g  = (const float*)d_in[17];
  const float* gn2_b  = (const float*)d_in[18];
  const float* down_w = (const float*)d_in[19];
  const float* down_b = (const float*)d_in[20];
  const float* gn3_g  = (const float*)d_in[21];
  const float* gn3_b  = (const float*)d_in[22];
  float* out = (float*)d_out;

  char* wsb = (char*)d_ws;
  __hip_bfloat16* R0h = (__hip_bfloat16*)wsb;             // 8 MB bf16 (y2 / down-out)
  float* R1f = (float*)(wsb + 16777216);                  // fp32 offmask / bf16 conv1-out
  __hip_bfloat16* R1h = (__hip_bfloat16*)(wsb + 16777216);
  __hip_bfloat16* R2 = (__hip_bfloat16*)(wsb + 33554432); // 8 MB bf16 (xs -> agg)
  __hip_bfloat16* R3 = (__hip_bfloat16*)(wsb + 41943040); // 8.92 MB bf16 (xp -> gn2pad)
  __hip_bfloat16* R4 = (__hip_bfloat16*)(wsb + 50864128); // 8.92 MB bf16 (t -> gn1pad)
  char* R5 = wsb + 59785216;
  __hip_bfloat16* w_inT  = (__hip_bfloat16*)R5;
  __hip_bfloat16* w_outT = (__hip_bfloat16*)(R5 + 131072);
  __hip_bfloat16* w_omT  = (__hip_bfloat16*)(R5 + 262144);
  __hip_bfloat16* c1T    = (__hip_bfloat16*)(R5 + 393216);
  __hip_bfloat16* dnT    = (__hip_bfloat16*)(R5 + 1572864);
  float* bias_om         = (float*)(R5 + 2752512);
  float* stats           = (float*)(R5 + 2753536);        // 768 floats: GN1|GN2|GN3

  // 0. fused prep (weights, offmask, R3 border, stats zero, NCHW->NHWC)
  k_prep<<<4643, 256, 0, stream>>>(x, w_in, w_out, conv1_w, down_w, w_off, w_mask, b_off, b_mask,
                                   w_inT, w_outT, c1T, dnT, w_omT, bias_om, stats, R3, R2);
  // 1. input_proj -> padded bf16 xp (R3)
  k_mm<0,1,1,256,0><<<dim3(256,2), 256, 0, stream>>>(R2, w_inT, b_in, nullptr, R3, nullptr);
  // 2. depthwise conv + LN + GELU -> t (R4 flat)
  k_dwln<<<2048, 256, 0, stream>>>(R2, dw_w, dw_b, ln_g, ln_b, R4);
  // 3. fused offset+mask GEMM -> R1 fp32
  k_mm<0,2,1,256,0><<<dim3(256,2), 256, 0, stream>>>(R4, w_omT, bias_om, R1f, nullptr, nullptr);
  // 4. sample -> agg (R2)
  k_sample<<<2048, 256, 0, stream>>>(R3, R1f, R2);
  // 5. output_proj -> R0 bf16 + GN1 stats
  k_mm<0,0,1,256,12><<<dim3(256,2), 256, 0, stream>>>(R2, w_outT, b_out, nullptr, R0h, stats);
  // 6. GN1 + SiLU -> padded bf16 (R4) + border
  k_gnapply<<<2048+130, 256, 0, stream>>>(R0h, stats, gn1_g, gn1_b, R4, 2048);
  // 7. conv1 -> R1 bf16 + GN2 stats
  k_mm<1,0,1,2304,12><<<dim3(256,2), 256, 0, stream>>>(R4, c1T, conv1_b, nullptr, R1h, stats+256);
  // 8. GN2 + SiLU -> padded bf16 (R3) + border
  k_gnapply<<<2048+130, 256, 0, stream>>>(R1h, stats+256, gn2_g, gn2_b, R3, 2048);
  // 9. down conv stride 2 -> R0 bf16 + GN3 stats
  k_mm<1,0,2,2304,10><<<dim3(64,2), 256, 0, stream>>>(R3, dnT, down_b, nullptr, R0h, stats+512);
  // 10. GN3 -> out NCHW fp32 (coalesced via LDS transpose)
  k_gnout<<<128, 256, 0, stream>>>(R0h, stats+512, gn3_g, gn3_b, out);
}